// Round 7
// baseline (259.660 us; speedup 1.0000x reference)
//
#include <hip/hip_runtime.h>
#include <hip/hip_bf16.h>

#define NEG 0.2f

typedef float vf4 __attribute__((ext_vector_type(4)));
typedef int   vi4 __attribute__((ext_vector_type(4)));
typedef unsigned int vu4 __attribute__((ext_vector_type(4)));

__device__ __forceinline__ float leaky(float x){ return x > 0.f ? x : NEG*x; }
__device__ __forceinline__ float sel4(float4 q, int head){
  float lo = (head & 1) ? q.y : q.x;
  float hi = (head & 1) ? q.w : q.z;
  return (head & 2) ? hi : lo;
}
__device__ __forceinline__ float b2f_lo(unsigned u){ return __uint_as_float(u << 16); }
__device__ __forceinline__ float b2f_hi(unsigned u){ return __uint_as_float(u & 0xffff0000u); }
__device__ __forceinline__ unsigned short f2b(float f){
  __hip_bfloat16 b = __float2bfloat16(f);
  return *(unsigned short*)&b;
}
__device__ __forceinline__ vf4 ntload_f4(const float* p){
  return __builtin_nontemporal_load((const vf4*)p);
}
__device__ __forceinline__ vi4 ntload_i4(const int* p){
  return __builtin_nontemporal_load((const vi4*)p);
}
__device__ __forceinline__ void ntstore_f4(float* p, float a, float b, float c, float d){
  vf4 v; v.x = a; v.y = b; v.z = c; v.w = d;
  __builtin_nontemporal_store(v, (vf4*)p);
}

// ---------------- K1: hf16 = bf16(h @ fcw^T), fused el/er ----------------
// grid.x = ceil(N/64). 256 threads. Both 64-feat halves per block.
// fc half in LDS (32KB, swizzled); h read directly (16-lane broadcast, L1).
__global__ __launch_bounds__(256) void k_proj(
    const float* __restrict__ h, const float* __restrict__ fcw,
    const float* __restrict__ attn_l, const float* __restrict__ attn_r,
    unsigned short* __restrict__ hf16, float* __restrict__ el, float* __restrict__ er, int N)
{
  __shared__ float fcs[64][128];
  const int tid = threadIdx.x;
  const int wave = tid >> 6, lane = tid & 63;
  const int fq = lane & 15, ng = lane >> 4;
  const int nb0 = blockIdx.x*64 + wave*16;

  // clamped row pointers for this lane's 4 nodes
  const float* hrow[4];
  #pragma unroll
  for (int j = 0; j < 4; ++j) {
    int gn = nb0 + ng*4 + j; if (gn >= N) gn = N-1;
    hrow[j] = &h[(size_t)gn*128];
  }

  for (int g = 0; g < 2; ++g) {
    if (g) __syncthreads();           // protect fcs before restage
    for (int i = tid; i < 64*32; i += 256) {
      int f = i >> 5, q = i & 31;
      float4 w = *(const float4*)&fcw[(size_t)(g*64 + f)*128 + 4*q];
      *(float4*)&fcs[f][4*(q ^ ((f>>2)&7))] = w;
    }
    __syncthreads();

    float acc[4][4];
    #pragma unroll
    for (int j = 0; j < 4; ++j)
      #pragma unroll
      for (int i = 0; i < 4; ++i) acc[j][i] = 0.f;

    #pragma unroll 8
    for (int kk = 0; kk < 32; ++kk) {
      const int qc = 4*(kk ^ (fq & 7));
      float4 r0 = *(const float4*)&fcs[4*fq + 0][qc];
      float4 r1 = *(const float4*)&fcs[4*fq + 1][qc];
      float4 r2 = *(const float4*)&fcs[4*fq + 2][qc];
      float4 r3 = *(const float4*)&fcs[4*fq + 3][qc];
      #pragma unroll
      for (int j = 0; j < 4; ++j) {
        vf4 hv = ntload_f4(&hrow[j][4*kk]);
        acc[j][0] += hv.x*r0.x + hv.y*r0.y + hv.z*r0.z + hv.w*r0.w;
        acc[j][1] += hv.x*r1.x + hv.y*r1.y + hv.z*r1.z + hv.w*r1.w;
        acc[j][2] += hv.x*r2.x + hv.y*r2.y + hv.z*r2.z + hv.w*r2.w;
        acc[j][3] += hv.x*r3.x + hv.y*r3.y + hv.z*r3.z + hv.w*r3.w;
      }
    }

    const float4 al4 = *(const float4*)&attn_l[g*64 + 4*fq];
    const float4 ar4 = *(const float4*)&attn_r[g*64 + 4*fq];
    #pragma unroll
    for (int j = 0; j < 4; ++j) {
      int gn = nb0 + ng*4 + j;
      float4 o = make_float4(acc[j][0], acc[j][1], acc[j][2], acc[j][3]);
      float elp = o.x*al4.x + o.y*al4.y + o.z*al4.z + o.w*al4.w;
      float erp = o.x*ar4.x + o.y*ar4.y + o.z*ar4.z + o.w*ar4.w;
      elp += __shfl_xor(elp, 1); elp += __shfl_xor(elp, 2); elp += __shfl_xor(elp, 4);
      erp += __shfl_xor(erp, 1); erp += __shfl_xor(erp, 2); erp += __shfl_xor(erp, 4);
      if (gn < N) {
        ushort4 ob;
        ob.x = f2b(o.x); ob.y = f2b(o.y); ob.z = f2b(o.z); ob.w = f2b(o.w);
        *(ushort4*)&hf16[(size_t)gn*128 + g*64 + 4*fq] = ob;
        if ((lane & 7) == 0) {
          int head = g*2 + ((lane >> 3) & 1);
          el[(size_t)gn*4 + head] = elp;
          er[(size_t)gn*4 + head] = erp;
        }
      }
    }
  }
}

// ---------------- CSR build ----------------
__global__ void k_hist(const int* __restrict__ dst, int* __restrict__ counts, int E) {
  int e = (blockIdx.x*256 + threadIdx.x)*4;
  if (e + 3 < E) {
    vi4 d = ntload_i4(&dst[e]);
    atomicAdd(&counts[d.x], 1); atomicAdd(&counts[d.y], 1);
    atomicAdd(&counts[d.z], 1); atomicAdd(&counts[d.w], 1);
  } else {
    for (int k = e; k < E; ++k) atomicAdd(&counts[dst[k]], 1);
  }
}

__global__ __launch_bounds__(256) void k_block_sums(const int* __restrict__ counts, int N, int* __restrict__ bsum) {
  __shared__ int tmp[256];
  int i = blockIdx.x*256 + threadIdx.x;
  tmp[threadIdx.x] = (i < N) ? counts[i] : 0;
  __syncthreads();
  for (int off = 128; off > 0; off >>= 1) {
    if (threadIdx.x < off) tmp[threadIdx.x] += tmp[threadIdx.x + off];
    __syncthreads();
  }
  if (threadIdx.x == 0) bsum[blockIdx.x] = tmp[0];
}

__global__ __launch_bounds__(256) void k_scan_partials(int* __restrict__ bsum, int nb) {
  __shared__ int tmp[256];
  int t = threadIdx.x;
  int v = (t < nb) ? bsum[t] : 0;
  tmp[t] = v;
  __syncthreads();
  for (int off = 1; off < 256; off <<= 1) {
    int x = (t >= off) ? tmp[t - off] : 0;
    __syncthreads();
    tmp[t] += x;
    __syncthreads();
  }
  if (t < nb) bsum[t] = tmp[t] - v;   // exclusive prefix of block sums
}

__global__ __launch_bounds__(256) void k_scan_chunks(const int* __restrict__ counts, int N,
    const int* __restrict__ bsum, int* __restrict__ offsets, int* __restrict__ cursor) {
  __shared__ int tmp[256];
  int t = threadIdx.x;
  int i = blockIdx.x*256 + t;
  int v = (i < N) ? counts[i] : 0;
  tmp[t] = v;
  __syncthreads();
  for (int off = 1; off < 256; off <<= 1) {
    int x = (t >= off) ? tmp[t - off] : 0;
    __syncthreads();
    tmp[t] += x;
    __syncthreads();
  }
  if (i < N) {
    int excl = tmp[t] - v + bsum[blockIdx.x];
    offsets[i] = excl;
    cursor[i]  = excl;
  }
}

// scatter only src values, sorted by dst.
// Data store via atomicExch: executes at the cache coherence point, so the
// random 4B writes aggregate into resident lines instead of 16x-amplified
// partial-line HBM writes.
__global__ void k_scatter(const int* __restrict__ dst, const int* __restrict__ src,
                          int* __restrict__ cursor, int* __restrict__ esrc, int E) {
  int e = (blockIdx.x*256 + threadIdx.x)*4;
  if (e + 3 < E) {
    vi4 d = ntload_i4(&dst[e]);
    vi4 s = ntload_i4(&src[e]);
    int p0 = atomicAdd(&cursor[d.x], 1);
    int p1 = atomicAdd(&cursor[d.y], 1);
    int p2 = atomicAdd(&cursor[d.z], 1);
    int p3 = atomicAdd(&cursor[d.w], 1);
    atomicExch(&esrc[p0], s.x);
    atomicExch(&esrc[p1], s.y);
    atomicExch(&esrc[p2], s.z);
    atomicExch(&esrc[p3], s.w);
  } else {
    for (int k = e; k < E; ++k) {
      int p = atomicAdd(&cursor[dst[k]], 1);
      atomicExch(&esrc[p], src[k]);
    }
  }
}

// ---------------- K2: per-dst softmax + aggregation (1 wave per node) ----------------
__global__ __launch_bounds__(256) void k_aggr(
    const int* __restrict__ esrc, const int* __restrict__ offsets, const int* __restrict__ counts,
    const unsigned short* __restrict__ hf16, const float* __restrict__ el, const float* __restrict__ er,
    float* __restrict__ out, float* __restrict__ mr, int N)
{
  __shared__ float as[4][64][4];
  __shared__ int   es[4][64];
  const int wave = threadIdx.x >> 6, lane = threadIdx.x & 63;
  const int v = blockIdx.x*4 + wave;
  if (v >= N) return;
  const int start = offsets[v];
  const int deg   = counts[v];
  const float4 er4 = *(const float4*)&er[(size_t)v*4];

  // ---- pass A: max + exp-sum (single gather for deg<=64), stash a in LDS ----
  const bool act = lane < deg;
  float4 e4 = make_float4(-1e30f, -1e30f, -1e30f, -1e30f);
  int mys = 0;
  if (act) {
    mys = esrc[start + lane];
    float4 el4 = *(const float4*)&el[(size_t)mys*4];
    e4.x = leaky(el4.x + er4.x);
    e4.y = leaky(el4.y + er4.y);
    e4.z = leaky(el4.z + er4.z);
    e4.w = leaky(el4.w + er4.w);
  }
  float4 m4 = e4;
  for (int j = lane + 64; j < deg; j += 64) {   // deg>64: essentially never
    int s = esrc[start + j];
    float4 el4 = *(const float4*)&el[(size_t)s*4];
    m4.x = fmaxf(m4.x, leaky(el4.x + er4.x));
    m4.y = fmaxf(m4.y, leaky(el4.y + er4.y));
    m4.z = fmaxf(m4.z, leaky(el4.z + er4.z));
    m4.w = fmaxf(m4.w, leaky(el4.w + er4.w));
  }
  #pragma unroll
  for (int mm = 32; mm; mm >>= 1) {
    m4.x = fmaxf(m4.x, __shfl_xor(m4.x, mm));
    m4.y = fmaxf(m4.y, __shfl_xor(m4.y, mm));
    m4.z = fmaxf(m4.z, __shfl_xor(m4.z, mm));
    m4.w = fmaxf(m4.w, __shfl_xor(m4.w, mm));
  }
  float4 x4 = make_float4(0.f, 0.f, 0.f, 0.f);
  if (act) {
    x4.x = __expf(e4.x - m4.x);
    x4.y = __expf(e4.y - m4.y);
    x4.z = __expf(e4.z - m4.z);
    x4.w = __expf(e4.w - m4.w);
  }
  float4 s4 = x4;
  for (int j = lane + 64; j < deg; j += 64) {   // rare
    int s = esrc[start + j];
    float4 el4 = *(const float4*)&el[(size_t)s*4];
    s4.x += __expf(leaky(el4.x + er4.x) - m4.x);
    s4.y += __expf(leaky(el4.y + er4.y) - m4.y);
    s4.z += __expf(leaky(el4.z + er4.z) - m4.z);
    s4.w += __expf(leaky(el4.w + er4.w) - m4.w);
  }
  #pragma unroll
  for (int mm = 32; mm; mm >>= 1) {
    s4.x += __shfl_xor(s4.x, mm);
    s4.y += __shfl_xor(s4.y, mm);
    s4.z += __shfl_xor(s4.z, mm);
    s4.w += __shfl_xor(s4.w, mm);
  }
  const float4 r4 = make_float4(1.f/s4.x, 1.f/s4.y, 1.f/s4.z, 1.f/s4.w);

  if (act) {
    float4 a4 = make_float4(x4.x*r4.x, x4.y*r4.y, x4.z*r4.z, x4.w*r4.w);
    *(float4*)&as[wave][lane][0] = a4;
    es[wave][lane] = mys;
  }
  // publish m,r for the coalesced a_out kernel
  if (lane == 0) *(float4*)&mr[(size_t)v*8]     = m4;
  if (lane == 1) *(float4*)&mr[(size_t)v*8 + 4] = r4;

  // ---- pass B: aggregate, 8 groups x 8 lanes, 2-deep pipelined (16 edges in flight) ----
  const int g = lane >> 3;      // edge slot 0..7
  const int l = lane & 7;       // feature sublane: feats 16l..16l+15
  const int head = l >> 1;
  float acc[16];
  #pragma unroll
  for (int k = 0; k < 16; ++k) acc[k] = 0.f;

  const int degL = deg < 64 ? deg : 64;
  {
    int je = g;
    int jec = je < degL ? je : 0;
    int sj = es[wave][jec];
    float a = je < degL ? as[wave][jec][head] : 0.f;
    const unsigned short* hp = &hf16[(size_t)sj*128 + 16*l];
    uint4 q0 = *(const uint4*)hp;
    uint4 q1 = *(const uint4*)(hp + 8);
    for (int j = 0; j < degL; j += 8) {
      // prefetch next group
      int je2 = j + 8 + g;
      int jec2 = je2 < degL ? je2 : 0;
      int s2 = es[wave][jec2];
      float a2 = je2 < degL ? as[wave][jec2][head] : 0.f;
      const unsigned short* hp2 = &hf16[(size_t)s2*128 + 16*l];
      uint4 p0 = *(const uint4*)hp2;
      uint4 p1 = *(const uint4*)(hp2 + 8);
      // fma current
      acc[0]  += a*b2f_lo(q0.x); acc[1]  += a*b2f_hi(q0.x);
      acc[2]  += a*b2f_lo(q0.y); acc[3]  += a*b2f_hi(q0.y);
      acc[4]  += a*b2f_lo(q0.z); acc[5]  += a*b2f_hi(q0.z);
      acc[6]  += a*b2f_lo(q0.w); acc[7]  += a*b2f_hi(q0.w);
      acc[8]  += a*b2f_lo(q1.x); acc[9]  += a*b2f_hi(q1.x);
      acc[10] += a*b2f_lo(q1.y); acc[11] += a*b2f_hi(q1.y);
      acc[12] += a*b2f_lo(q1.z); acc[13] += a*b2f_hi(q1.z);
      acc[14] += a*b2f_lo(q1.w); acc[15] += a*b2f_hi(q1.w);
      q0 = p0; q1 = p1; a = a2;
    }
  }
  for (int j = 64; j < deg; j += 8) {   // deg>64 fallback: recompute a
    const int je = j + g;
    const bool valid = je < deg;
    int s = esrc[start + (valid ? je : 0)];
    float mh  = sel4(m4, head), rh = sel4(r4, head), erh = sel4(er4, head);
    float a = __expf(leaky(el[(size_t)s*4 + head] + erh) - mh) * rh;
    if (!valid) a = 0.f;
    const unsigned short* hp = &hf16[(size_t)s*128 + 16*l];
    uint4 q0 = *(const uint4*)hp;
    uint4 q1 = *(const uint4*)(hp + 8);
    acc[0]  += a*b2f_lo(q0.x); acc[1]  += a*b2f_hi(q0.x);
    acc[2]  += a*b2f_lo(q0.y); acc[3]  += a*b2f_hi(q0.y);
    acc[4]  += a*b2f_lo(q0.z); acc[5]  += a*b2f_hi(q0.z);
    acc[6]  += a*b2f_lo(q0.w); acc[7]  += a*b2f_hi(q0.w);
    acc[8]  += a*b2f_lo(q1.x); acc[9]  += a*b2f_hi(q1.x);
    acc[10] += a*b2f_lo(q1.y); acc[11] += a*b2f_hi(q1.y);
    acc[12] += a*b2f_lo(q1.z); acc[13] += a*b2f_hi(q1.z);
    acc[14] += a*b2f_lo(q1.w); acc[15] += a*b2f_hi(q1.w);
  }

  #pragma unroll
  for (int k = 0; k < 16; ++k) {
    acc[k] += __shfl_xor(acc[k], 8);
    acc[k] += __shfl_xor(acc[k], 16);
    acc[k] += __shfl_xor(acc[k], 32);
  }
  if (g == 0) {
    float* op = &out[(size_t)v*128 + 16*l];
    ntstore_f4(op,      acc[0],  acc[1],  acc[2],  acc[3]);
    ntstore_f4(op + 4,  acc[4],  acc[5],  acc[6],  acc[7]);
    ntstore_f4(op + 8,  acc[8],  acc[9],  acc[10], acc[11]);
    ntstore_f4(op + 12, acc[12], acc[13], acc[14], acc[15]);
  }
}

// ---------------- K3: coalesced attention output (original edge order) ----------------
__global__ void k_attn(const int* __restrict__ src, const int* __restrict__ dst,
                       const float* __restrict__ el, const float* __restrict__ er,
                       const float* __restrict__ mr, float* __restrict__ a_out, int E) {
  int e = blockIdx.x*256 + threadIdx.x;
  if (e >= E) return;
  int s = __builtin_nontemporal_load(&src[e]);
  int d = __builtin_nontemporal_load(&dst[e]);
  float4 el4 = *(const float4*)&el[(size_t)s*4];
  float4 er4 = *(const float4*)&er[(size_t)d*4];
  float4 m4  = *(const float4*)&mr[(size_t)d*8];
  float4 r4  = *(const float4*)&mr[(size_t)d*8 + 4];
  float ax = __expf(leaky(el4.x + er4.x) - m4.x) * r4.x;
  float ay = __expf(leaky(el4.y + er4.y) - m4.y) * r4.y;
  float az = __expf(leaky(el4.z + er4.z) - m4.z) * r4.z;
  float aw = __expf(leaky(el4.w + er4.w) - m4.w) * r4.w;
  ntstore_f4(&a_out[(size_t)e*4], ax, ay, az, aw);
}

extern "C" void kernel_launch(void* const* d_in, const int* in_sizes, int n_in,
                              void* d_out, int out_size, void* d_ws, size_t ws_size,
                              hipStream_t stream) {
  const float* h      = (const float*)d_in[0];
  const float* fcw    = (const float*)d_in[1];
  const float* attn_l = (const float*)d_in[2];
  const float* attn_r = (const float*)d_in[3];
  const int*   src    = (const int*)d_in[4];
  const int*   dst    = (const int*)d_in[5];
  const int N = in_sizes[0] / 128;
  const int E = in_sizes[4];

  float* out   = (float*)d_out;
  float* a_out = out + (size_t)N*128;

  char* w = (char*)d_ws;
  unsigned short* hf16 = (unsigned short*)w; w += (size_t)N*128*sizeof(unsigned short);
  float* el      = (float*)w; w += (size_t)N*4*sizeof(float);
  float* er      = (float*)w; w += (size_t)N*4*sizeof(float);
  float* mr      = (float*)w; w += (size_t)N*8*sizeof(float);
  int*   esrc    = (int*)w;   w += (size_t)E*sizeof(int);
  int*   counts  = (int*)w;   w += (size_t)N*sizeof(int);
  int*   offsets = (int*)w;   w += (size_t)N*sizeof(int);
  int*   cursor  = (int*)w;   w += (size_t)N*sizeof(int);
  int*   bsum    = (int*)w;   w += 256*sizeof(int);

  hipMemsetAsync(counts, 0, (size_t)N*sizeof(int), stream);

  k_proj<<<(N + 63)/64, 256, 0, stream>>>(h, fcw, attn_l, attn_r, hf16, el, er, N);

  int eth = (E + 3)/4;
  int ebl = (eth + 255)/256;
  k_hist<<<ebl, 256, 0, stream>>>(dst, counts, E);

  int NB = (N + 255)/256;
  k_block_sums<<<NB, 256, 0, stream>>>(counts, N, bsum);
  k_scan_partials<<<1, 256, 0, stream>>>(bsum, NB);
  k_scan_chunks<<<NB, 256, 0, stream>>>(counts, N, bsum, offsets, cursor);

  k_scatter<<<ebl, 256, 0, stream>>>(dst, src, cursor, esrc, E);

  k_aggr<<<(N + 3)/4, 256, 0, stream>>>(esrc, offsets, counts, hf16, el, er, out, mr, N);

  k_attn<<<(E + 255)/256, 256, 0, stream>>>(src, dst, el, er, mr, a_out, E);
}

// Round 8
// 198.261 us; speedup vs baseline: 1.3097x; 1.3097x over previous
//
#include <hip/hip_runtime.h>
#include <hip/hip_bf16.h>

#define NEG 0.2f

typedef float vf4 __attribute__((ext_vector_type(4)));
typedef int   vi4 __attribute__((ext_vector_type(4)));

__device__ __forceinline__ float leaky(float x){ return x > 0.f ? x : NEG*x; }
__device__ __forceinline__ float sel4(float4 q, int head){
  float lo = (head & 1) ? q.y : q.x;
  float hi = (head & 1) ? q.w : q.z;
  return (head & 2) ? hi : lo;
}
__device__ __forceinline__ float b2f_lo(unsigned u){ return __uint_as_float(u << 16); }
__device__ __forceinline__ float b2f_hi(unsigned u){ return __uint_as_float(u & 0xffff0000u); }
__device__ __forceinline__ unsigned short f2b(float f){
  __hip_bfloat16 b = __float2bfloat16(f);
  return *(unsigned short*)&b;
}
__device__ __forceinline__ vf4 ntload_f4(const float* p){
  return __builtin_nontemporal_load((const vf4*)p);
}
__device__ __forceinline__ vi4 ntload_i4(const int* p){
  return __builtin_nontemporal_load((const vi4*)p);
}
__device__ __forceinline__ void ntstore_f4(float* p, float a, float b, float c, float d){
  vf4 v; v.x = a; v.y = b; v.z = c; v.w = d;
  __builtin_nontemporal_store(v, (vf4*)p);
}

// ---------------- K1: hf16 = bf16(h @ fcw^T), fused el/er ----------------
__global__ __launch_bounds__(256) void k_proj(
    const float* __restrict__ h, const float* __restrict__ fcw,
    const float* __restrict__ attn_l, const float* __restrict__ attn_r,
    unsigned short* __restrict__ hf16, float* __restrict__ el, float* __restrict__ er, int N)
{
  __shared__ float fcs[64][128];
  const int tid = threadIdx.x;
  const int wave = tid >> 6, lane = tid & 63;
  const int fq = lane & 15, ng = lane >> 4;
  const int nb0 = blockIdx.x*64 + wave*16;

  const float* hrow[4];
  #pragma unroll
  for (int j = 0; j < 4; ++j) {
    int gn = nb0 + ng*4 + j; if (gn >= N) gn = N-1;
    hrow[j] = &h[(size_t)gn*128];
  }

  for (int g = 0; g < 2; ++g) {
    if (g) __syncthreads();
    for (int i = tid; i < 64*32; i += 256) {
      int f = i >> 5, q = i & 31;
      float4 w = *(const float4*)&fcw[(size_t)(g*64 + f)*128 + 4*q];
      *(float4*)&fcs[f][4*(q ^ ((f>>2)&7))] = w;
    }
    __syncthreads();

    float acc[4][4];
    #pragma unroll
    for (int j = 0; j < 4; ++j)
      #pragma unroll
      for (int i = 0; i < 4; ++i) acc[j][i] = 0.f;

    #pragma unroll 8
    for (int kk = 0; kk < 32; ++kk) {
      const int qc = 4*(kk ^ (fq & 7));
      float4 r0 = *(const float4*)&fcs[4*fq + 0][qc];
      float4 r1 = *(const float4*)&fcs[4*fq + 1][qc];
      float4 r2 = *(const float4*)&fcs[4*fq + 2][qc];
      float4 r3 = *(const float4*)&fcs[4*fq + 3][qc];
      #pragma unroll
      for (int j = 0; j < 4; ++j) {
        vf4 hv = ntload_f4(&hrow[j][4*kk]);
        acc[j][0] += hv.x*r0.x + hv.y*r0.y + hv.z*r0.z + hv.w*r0.w;
        acc[j][1] += hv.x*r1.x + hv.y*r1.y + hv.z*r1.z + hv.w*r1.w;
        acc[j][2] += hv.x*r2.x + hv.y*r2.y + hv.z*r2.z + hv.w*r2.w;
        acc[j][3] += hv.x*r3.x + hv.y*r3.y + hv.z*r3.z + hv.w*r3.w;
      }
    }

    const float4 al4 = *(const float4*)&attn_l[g*64 + 4*fq];
    const float4 ar4 = *(const float4*)&attn_r[g*64 + 4*fq];
    #pragma unroll
    for (int j = 0; j < 4; ++j) {
      int gn = nb0 + ng*4 + j;
      float4 o = make_float4(acc[j][0], acc[j][1], acc[j][2], acc[j][3]);
      float elp = o.x*al4.x + o.y*al4.y + o.z*al4.z + o.w*al4.w;
      float erp = o.x*ar4.x + o.y*ar4.y + o.z*ar4.z + o.w*ar4.w;
      elp += __shfl_xor(elp, 1); elp += __shfl_xor(elp, 2); elp += __shfl_xor(elp, 4);
      erp += __shfl_xor(erp, 1); erp += __shfl_xor(erp, 2); erp += __shfl_xor(erp, 4);
      if (gn < N) {
        ushort4 ob;
        ob.x = f2b(o.x); ob.y = f2b(o.y); ob.z = f2b(o.z); ob.w = f2b(o.w);
        *(ushort4*)&hf16[(size_t)gn*128 + g*64 + 4*fq] = ob;
        if ((lane & 7) == 0) {
          int head = g*2 + ((lane >> 3) & 1);
          el[(size_t)gn*4 + head] = elp;
          er[(size_t)gn*4 + head] = erp;
        }
      }
    }
  }
}

// ---------------- CSR build ----------------
__global__ void k_hist(const int* __restrict__ dst, int* __restrict__ counts, int E) {
  int e = (blockIdx.x*256 + threadIdx.x)*4;
  if (e + 3 < E) {
    vi4 d = ntload_i4(&dst[e]);
    atomicAdd(&counts[d.x], 1); atomicAdd(&counts[d.y], 1);
    atomicAdd(&counts[d.z], 1); atomicAdd(&counts[d.w], 1);
  } else {
    for (int k = e; k < E; ++k) atomicAdd(&counts[dst[k]], 1);
  }
}

__global__ __launch_bounds__(256) void k_block_sums(const int* __restrict__ counts, int N, int* __restrict__ bsum) {
  __shared__ int tmp[256];
  int i = blockIdx.x*256 + threadIdx.x;
  tmp[threadIdx.x] = (i < N) ? counts[i] : 0;
  __syncthreads();
  for (int off = 128; off > 0; off >>= 1) {
    if (threadIdx.x < off) tmp[threadIdx.x] += tmp[threadIdx.x + off];
    __syncthreads();
  }
  if (threadIdx.x == 0) bsum[blockIdx.x] = tmp[0];
}

__global__ __launch_bounds__(256) void k_scan_partials(int* __restrict__ bsum, int nb) {
  __shared__ int tmp[256];
  int t = threadIdx.x;
  int v = (t < nb) ? bsum[t] : 0;
  tmp[t] = v;
  __syncthreads();
  for (int off = 1; off < 256; off <<= 1) {
    int x = (t >= off) ? tmp[t - off] : 0;
    __syncthreads();
    tmp[t] += x;
    __syncthreads();
  }
  if (t < nb) bsum[t] = tmp[t] - v;
}

__global__ __launch_bounds__(256) void k_scan_chunks(const int* __restrict__ counts, int N,
    const int* __restrict__ bsum, int* __restrict__ offsets) {
  __shared__ int tmp[256];
  int t = threadIdx.x;
  int i = blockIdx.x*256 + t;
  int v = (i < N) ? counts[i] : 0;
  tmp[t] = v;
  __syncthreads();
  for (int off = 1; off < 256; off <<= 1) {
    int x = (t >= off) ? tmp[t - off] : 0;
    __syncthreads();
    tmp[t] += x;
    __syncthreads();
  }
  if (i < N) offsets[i] = tmp[t] - v + bsum[blockIdx.x];
}

// bucket cursors: bcur[b] = offsets[b*256]  (bucket = dst>>8, contiguous dst range)
__global__ void k_binit(const int* __restrict__ offsets, int* __restrict__ bcur, int B) {
  int b = threadIdx.x;
  if (b < B) bcur[b] = offsets[b << 8];
}

// ---------------- pass 1: bin edges by bucket (LDS sort, coalesced staging writes) ----
// staging word: (dst&255)<<24 | src   (src < 2^24)
#define TILE 4096
__global__ __launch_bounds__(1024) void k_bin(
    const int* __restrict__ src, const int* __restrict__ dst,
    int* __restrict__ bcur, unsigned int* __restrict__ staging, int E)
{
  __shared__ unsigned int lpack[TILE];
  __shared__ unsigned char lbkt[TILE];
  __shared__ unsigned short sidx[TILE];
  __shared__ int lhist[256], lbase[256], lcur[256], gbase[256];

  const int t = threadIdx.x;
  const int e0 = blockIdx.x * TILE;
  const int cnt = min(TILE, E - e0);

  if (t < 256) lhist[t] = 0;
  __syncthreads();

  for (int i = t; i < cnt; i += 1024) {
    int s = __builtin_nontemporal_load(&src[e0 + i]);
    int d = __builtin_nontemporal_load(&dst[e0 + i]);
    lpack[i] = ((unsigned)(d & 255) << 24) | (unsigned)s;
    int b = d >> 8;
    lbkt[i] = (unsigned char)b;
    atomicAdd(&lhist[b], 1);
  }
  __syncthreads();

  // exclusive scan of lhist -> lbase
  __shared__ int ltmp[256];
  if (t < 256) ltmp[t] = lhist[t];
  __syncthreads();
  for (int off = 1; off < 256; off <<= 1) {
    int x = 0;
    if (t < 256 && t >= off) x = ltmp[t - off];
    __syncthreads();
    if (t < 256) ltmp[t] += x;
    __syncthreads();
  }
  if (t < 256) { lbase[t] = ltmp[t] - lhist[t]; lcur[t] = ltmp[t] - lhist[t]; }
  __syncthreads();

  // local permutation: sidx[pos] = i, pos grouped by bucket
  for (int i = t; i < cnt; i += 1024) {
    int p = atomicAdd(&lcur[lbkt[i]], 1);
    sidx[p] = (unsigned short)i;
  }
  // reserve global runs per bucket
  if (t < 256) {
    int c = lhist[t];
    gbase[t] = c ? atomicAdd(&bcur[t], c) : 0;
  }
  __syncthreads();

  // write staging in bucket-sorted order: consecutive p -> consecutive addr
  for (int p = t; p < cnt; p += 1024) {
    int j = sidx[p];
    int b = lbkt[j];
    staging[gbase[b] + (p - lbase[b])] = lpack[j];
  }
}

// ---------------- pass 2: per-bucket counting sort -> esrc (coalesced) ----------------
#define BKT_CAP 8192
__global__ __launch_bounds__(1024) void k_debin(
    const unsigned int* __restrict__ staging, const int* __restrict__ offsets,
    int* __restrict__ esrc, int N, int E)
{
  __shared__ int lout[BKT_CAP];
  __shared__ int lcur2[256];

  const int t = threadIdx.x;
  const int b = blockIdx.x;
  const int n0 = b << 8;
  const int nb = min(256, N - n0);
  const int out_start = offsets[n0];
  const int end = (n0 + 256 < N) ? offsets[n0 + 256] : E;
  const int cnt = end - out_start;

  if (t < nb) lcur2[t] = offsets[n0 + t] - out_start;
  __syncthreads();

  if (cnt <= BKT_CAP) {
    for (int i = t; i < cnt; i += 1024) {
      unsigned int w = staging[out_start + i];
      int p = atomicAdd(&lcur2[w >> 24], 1);
      lout[p] = (int)(w & 0x00FFFFFFu);
    }
    __syncthreads();
    for (int i = t; i < cnt; i += 1024)
      esrc[out_start + i] = lout[i];
  } else {
    // overflow fallback (not expected with this data): direct scatter
    for (int i = t; i < cnt; i += 1024) {
      unsigned int w = staging[out_start + i];
      int p = atomicAdd(&lcur2[w >> 24], 1);
      esrc[out_start + p] = (int)(w & 0x00FFFFFFu);
    }
  }
}

// ---------------- K2: per-dst softmax + aggregation (1 wave per node) ----------------
__global__ __launch_bounds__(256) void k_aggr(
    const int* __restrict__ esrc, const int* __restrict__ offsets, const int* __restrict__ counts,
    const unsigned short* __restrict__ hf16, const float* __restrict__ el, const float* __restrict__ er,
    float* __restrict__ out, float* __restrict__ mr, int N)
{
  __shared__ float as[4][64][4];
  __shared__ int   es[4][64];
  const int wave = threadIdx.x >> 6, lane = threadIdx.x & 63;
  const int v = blockIdx.x*4 + wave;
  if (v >= N) return;
  const int start = offsets[v];
  const int deg   = counts[v];
  const float4 er4 = *(const float4*)&er[(size_t)v*4];

  const bool act = lane < deg;
  float4 e4 = make_float4(-1e30f, -1e30f, -1e30f, -1e30f);
  int mys = 0;
  if (act) {
    mys = esrc[start + lane];
    float4 el4 = *(const float4*)&el[(size_t)mys*4];
    e4.x = leaky(el4.x + er4.x);
    e4.y = leaky(el4.y + er4.y);
    e4.z = leaky(el4.z + er4.z);
    e4.w = leaky(el4.w + er4.w);
  }
  float4 m4 = e4;
  for (int j = lane + 64; j < deg; j += 64) {
    int s = esrc[start + j];
    float4 el4 = *(const float4*)&el[(size_t)s*4];
    m4.x = fmaxf(m4.x, leaky(el4.x + er4.x));
    m4.y = fmaxf(m4.y, leaky(el4.y + er4.y));
    m4.z = fmaxf(m4.z, leaky(el4.z + er4.z));
    m4.w = fmaxf(m4.w, leaky(el4.w + er4.w));
  }
  #pragma unroll
  for (int mm = 32; mm; mm >>= 1) {
    m4.x = fmaxf(m4.x, __shfl_xor(m4.x, mm));
    m4.y = fmaxf(m4.y, __shfl_xor(m4.y, mm));
    m4.z = fmaxf(m4.z, __shfl_xor(m4.z, mm));
    m4.w = fmaxf(m4.w, __shfl_xor(m4.w, mm));
  }
  float4 x4 = make_float4(0.f, 0.f, 0.f, 0.f);
  if (act) {
    x4.x = __expf(e4.x - m4.x);
    x4.y = __expf(e4.y - m4.y);
    x4.z = __expf(e4.z - m4.z);
    x4.w = __expf(e4.w - m4.w);
  }
  float4 s4 = x4;
  for (int j = lane + 64; j < deg; j += 64) {
    int s = esrc[start + j];
    float4 el4 = *(const float4*)&el[(size_t)s*4];
    s4.x += __expf(leaky(el4.x + er4.x) - m4.x);
    s4.y += __expf(leaky(el4.y + er4.y) - m4.y);
    s4.z += __expf(leaky(el4.z + er4.z) - m4.z);
    s4.w += __expf(leaky(el4.w + er4.w) - m4.w);
  }
  #pragma unroll
  for (int mm = 32; mm; mm >>= 1) {
    s4.x += __shfl_xor(s4.x, mm);
    s4.y += __shfl_xor(s4.y, mm);
    s4.z += __shfl_xor(s4.z, mm);
    s4.w += __shfl_xor(s4.w, mm);
  }
  const float4 r4 = make_float4(1.f/s4.x, 1.f/s4.y, 1.f/s4.z, 1.f/s4.w);

  if (act) {
    float4 a4 = make_float4(x4.x*r4.x, x4.y*r4.y, x4.z*r4.z, x4.w*r4.w);
    *(float4*)&as[wave][lane][0] = a4;
    es[wave][lane] = mys;
  }
  if (lane == 0) *(float4*)&mr[(size_t)v*8]     = m4;
  if (lane == 1) *(float4*)&mr[(size_t)v*8 + 4] = r4;

  const int g = lane >> 3;
  const int l = lane & 7;
  const int head = l >> 1;
  float acc[16];
  #pragma unroll
  for (int k = 0; k < 16; ++k) acc[k] = 0.f;

  const int degL = deg < 64 ? deg : 64;
  {
    int je = g;
    int jec = je < degL ? je : 0;
    int sj = es[wave][jec];
    float a = je < degL ? as[wave][jec][head] : 0.f;
    const unsigned short* hp = &hf16[(size_t)sj*128 + 16*l];
    uint4 q0 = *(const uint4*)hp;
    uint4 q1 = *(const uint4*)(hp + 8);
    for (int j = 0; j < degL; j += 8) {
      int je2 = j + 8 + g;
      int jec2 = je2 < degL ? je2 : 0;
      int s2 = es[wave][jec2];
      float a2 = je2 < degL ? as[wave][jec2][head] : 0.f;
      const unsigned short* hp2 = &hf16[(size_t)s2*128 + 16*l];
      uint4 p0 = *(const uint4*)hp2;
      uint4 p1 = *(const uint4*)(hp2 + 8);
      acc[0]  += a*b2f_lo(q0.x); acc[1]  += a*b2f_hi(q0.x);
      acc[2]  += a*b2f_lo(q0.y); acc[3]  += a*b2f_hi(q0.y);
      acc[4]  += a*b2f_lo(q0.z); acc[5]  += a*b2f_hi(q0.z);
      acc[6]  += a*b2f_lo(q0.w); acc[7]  += a*b2f_hi(q0.w);
      acc[8]  += a*b2f_lo(q1.x); acc[9]  += a*b2f_hi(q1.x);
      acc[10] += a*b2f_lo(q1.y); acc[11] += a*b2f_hi(q1.y);
      acc[12] += a*b2f_lo(q1.z); acc[13] += a*b2f_hi(q1.z);
      acc[14] += a*b2f_lo(q1.w); acc[15] += a*b2f_hi(q1.w);
      q0 = p0; q1 = p1; a = a2;
    }
  }
  for (int j = 64; j < deg; j += 8) {
    const int je = j + g;
    const bool valid = je < deg;
    int s = esrc[start + (valid ? je : 0)];
    float mh  = sel4(m4, head), rh = sel4(r4, head), erh = sel4(er4, head);
    float a = __expf(leaky(el[(size_t)s*4 + head] + erh) - mh) * rh;
    if (!valid) a = 0.f;
    const unsigned short* hp = &hf16[(size_t)s*128 + 16*l];
    uint4 q0 = *(const uint4*)hp;
    uint4 q1 = *(const uint4*)(hp + 8);
    acc[0]  += a*b2f_lo(q0.x); acc[1]  += a*b2f_hi(q0.x);
    acc[2]  += a*b2f_lo(q0.y); acc[3]  += a*b2f_hi(q0.y);
    acc[4]  += a*b2f_lo(q0.z); acc[5]  += a*b2f_hi(q0.z);
    acc[6]  += a*b2f_lo(q0.w); acc[7]  += a*b2f_hi(q0.w);
    acc[8]  += a*b2f_lo(q1.x); acc[9]  += a*b2f_hi(q1.x);
    acc[10] += a*b2f_lo(q1.y); acc[11] += a*b2f_hi(q1.y);
    acc[12] += a*b2f_lo(q1.z); acc[13] += a*b2f_hi(q1.z);
    acc[14] += a*b2f_lo(q1.w); acc[15] += a*b2f_hi(q1.w);
  }

  #pragma unroll
  for (int k = 0; k < 16; ++k) {
    acc[k] += __shfl_xor(acc[k], 8);
    acc[k] += __shfl_xor(acc[k], 16);
    acc[k] += __shfl_xor(acc[k], 32);
  }
  if (g == 0) {
    float* op = &out[(size_t)v*128 + 16*l];
    ntstore_f4(op,      acc[0],  acc[1],  acc[2],  acc[3]);
    ntstore_f4(op + 4,  acc[4],  acc[5],  acc[6],  acc[7]);
    ntstore_f4(op + 8,  acc[8],  acc[9],  acc[10], acc[11]);
    ntstore_f4(op + 12, acc[12], acc[13], acc[14], acc[15]);
  }
}

// ---------------- K3: coalesced attention output (original edge order) ----------------
__global__ void k_attn(const int* __restrict__ src, const int* __restrict__ dst,
                       const float* __restrict__ el, const float* __restrict__ er,
                       const float* __restrict__ mr, float* __restrict__ a_out, int E) {
  int e = blockIdx.x*256 + threadIdx.x;
  if (e >= E) return;
  int s = __builtin_nontemporal_load(&src[e]);
  int d = __builtin_nontemporal_load(&dst[e]);
  float4 el4 = *(const float4*)&el[(size_t)s*4];
  float4 er4 = *(const float4*)&er[(size_t)d*4];
  float4 m4  = *(const float4*)&mr[(size_t)d*8];
  float4 r4  = *(const float4*)&mr[(size_t)d*8 + 4];
  float ax = __expf(leaky(el4.x + er4.x) - m4.x) * r4.x;
  float ay = __expf(leaky(el4.y + er4.y) - m4.y) * r4.y;
  float az = __expf(leaky(el4.z + er4.z) - m4.z) * r4.z;
  float aw = __expf(leaky(el4.w + er4.w) - m4.w) * r4.w;
  ntstore_f4(&a_out[(size_t)e*4], ax, ay, az, aw);
}

extern "C" void kernel_launch(void* const* d_in, const int* in_sizes, int n_in,
                              void* d_out, int out_size, void* d_ws, size_t ws_size,
                              hipStream_t stream) {
  const float* h      = (const float*)d_in[0];
  const float* fcw    = (const float*)d_in[1];
  const float* attn_l = (const float*)d_in[2];
  const float* attn_r = (const float*)d_in[3];
  const int*   src    = (const int*)d_in[4];
  const int*   dst    = (const int*)d_in[5];
  const int N = in_sizes[0] / 128;
  const int E = in_sizes[4];
  const int B = (N + 255) >> 8;    // buckets (assumes N <= 65536)

  float* out   = (float*)d_out;
  float* a_out = out + (size_t)N*128;

  char* w = (char*)d_ws;
  unsigned short* hf16 = (unsigned short*)w; w += (size_t)N*128*sizeof(unsigned short);
  float* el      = (float*)w; w += (size_t)N*4*sizeof(float);
  float* er      = (float*)w; w += (size_t)N*4*sizeof(float);
  float* mr      = (float*)w; w += (size_t)N*8*sizeof(float);
  int*   esrc    = (int*)w;   w += (size_t)E*sizeof(int);
  unsigned int* staging = (unsigned int*)w; w += (size_t)E*sizeof(unsigned int);
  int*   counts  = (int*)w;   w += (size_t)N*sizeof(int);
  int*   offsets = (int*)w;   w += (size_t)N*sizeof(int);
  int*   bcur    = (int*)w;   w += 256*sizeof(int);
  int*   bsum    = (int*)w;   w += 256*sizeof(int);

  hipMemsetAsync(counts, 0, (size_t)N*sizeof(int), stream);

  k_proj<<<(N + 63)/64, 256, 0, stream>>>(h, fcw, attn_l, attn_r, hf16, el, er, N);

  int eth = (E + 3)/4;
  int ebl = (eth + 255)/256;
  k_hist<<<ebl, 256, 0, stream>>>(dst, counts, E);

  int NB = (N + 255)/256;
  k_block_sums<<<NB, 256, 0, stream>>>(counts, N, bsum);
  k_scan_partials<<<1, 256, 0, stream>>>(bsum, NB);
  k_scan_chunks<<<NB, 256, 0, stream>>>(counts, N, bsum, offsets);

  k_binit<<<1, 256, 0, stream>>>(offsets, bcur, B);
  k_bin<<<(E + TILE - 1)/TILE, 1024, 0, stream>>>(src, dst, bcur, staging, E);
  k_debin<<<B, 1024, 0, stream>>>(staging, offsets, esrc, N, E);

  k_aggr<<<(N + 3)/4, 256, 0, stream>>>(esrc, offsets, counts, hf16, el, er, out, mr, N);

  k_attn<<<(E + 255)/256, 256, 0, stream>>>(src, dst, el, er, mr, a_out, E);
}

// Round 9
// 169.880 us; speedup vs baseline: 1.5285x; 1.1671x over previous
//
#include <hip/hip_runtime.h>
#include <hip/hip_bf16.h>

#define NEG 0.2f

typedef float vf4 __attribute__((ext_vector_type(4)));
typedef int   vi4 __attribute__((ext_vector_type(4)));

__device__ __forceinline__ float leaky(float x){ return x > 0.f ? x : NEG*x; }
__device__ __forceinline__ float sel4(float4 q, int head){
  float lo = (head & 1) ? q.y : q.x;
  float hi = (head & 1) ? q.w : q.z;
  return (head & 2) ? hi : lo;
}
__device__ __forceinline__ float b2f_lo(unsigned u){ return __uint_as_float(u << 16); }
__device__ __forceinline__ float b2f_hi(unsigned u){ return __uint_as_float(u & 0xffff0000u); }
__device__ __forceinline__ unsigned short f2b(float f){
  __hip_bfloat16 b = __float2bfloat16(f);
  return *(unsigned short*)&b;
}
__device__ __forceinline__ vf4 ntload_f4(const float* p){
  return __builtin_nontemporal_load((const vf4*)p);
}
__device__ __forceinline__ vi4 ntload_i4(const int* p){
  return __builtin_nontemporal_load((const vi4*)p);
}
__device__ __forceinline__ void ntstore_f4(float* p, float a, float b, float c, float d){
  vf4 v; v.x = a; v.y = b; v.z = c; v.w = d;
  __builtin_nontemporal_store(v, (vf4*)p);
}

// ---------------- K1: hf16 = bf16(h @ fcw^T), fused el/er ----------------
__global__ __launch_bounds__(256) void k_proj(
    const float* __restrict__ h, const float* __restrict__ fcw,
    const float* __restrict__ attn_l, const float* __restrict__ attn_r,
    unsigned short* __restrict__ hf16, float* __restrict__ el, float* __restrict__ er, int N)
{
  __shared__ float fcs[64][128];
  const int tid = threadIdx.x;
  const int wave = tid >> 6, lane = tid & 63;
  const int fq = lane & 15, ng = lane >> 4;
  const int nb0 = blockIdx.x*64 + wave*16;

  const float* hrow[4];
  #pragma unroll
  for (int j = 0; j < 4; ++j) {
    int gn = nb0 + ng*4 + j; if (gn >= N) gn = N-1;
    hrow[j] = &h[(size_t)gn*128];
  }

  for (int g = 0; g < 2; ++g) {
    if (g) __syncthreads();
    for (int i = tid; i < 64*32; i += 256) {
      int f = i >> 5, q = i & 31;
      float4 w = *(const float4*)&fcw[(size_t)(g*64 + f)*128 + 4*q];
      *(float4*)&fcs[f][4*(q ^ ((f>>2)&7))] = w;
    }
    __syncthreads();

    float acc[4][4];
    #pragma unroll
    for (int j = 0; j < 4; ++j)
      #pragma unroll
      for (int i = 0; i < 4; ++i) acc[j][i] = 0.f;

    #pragma unroll 8
    for (int kk = 0; kk < 32; ++kk) {
      const int qc = 4*(kk ^ (fq & 7));
      float4 r0 = *(const float4*)&fcs[4*fq + 0][qc];
      float4 r1 = *(const float4*)&fcs[4*fq + 1][qc];
      float4 r2 = *(const float4*)&fcs[4*fq + 2][qc];
      float4 r3 = *(const float4*)&fcs[4*fq + 3][qc];
      #pragma unroll
      for (int j = 0; j < 4; ++j) {
        vf4 hv = ntload_f4(&hrow[j][4*kk]);
        acc[j][0] += hv.x*r0.x + hv.y*r0.y + hv.z*r0.z + hv.w*r0.w;
        acc[j][1] += hv.x*r1.x + hv.y*r1.y + hv.z*r1.z + hv.w*r1.w;
        acc[j][2] += hv.x*r2.x + hv.y*r2.y + hv.z*r2.z + hv.w*r2.w;
        acc[j][3] += hv.x*r3.x + hv.y*r3.y + hv.z*r3.z + hv.w*r3.w;
      }
    }

    const float4 al4 = *(const float4*)&attn_l[g*64 + 4*fq];
    const float4 ar4 = *(const float4*)&attn_r[g*64 + 4*fq];
    #pragma unroll
    for (int j = 0; j < 4; ++j) {
      int gn = nb0 + ng*4 + j;
      float4 o = make_float4(acc[j][0], acc[j][1], acc[j][2], acc[j][3]);
      float elp = o.x*al4.x + o.y*al4.y + o.z*al4.z + o.w*al4.w;
      float erp = o.x*ar4.x + o.y*ar4.y + o.z*ar4.z + o.w*ar4.w;
      elp += __shfl_xor(elp, 1); elp += __shfl_xor(elp, 2); elp += __shfl_xor(elp, 4);
      erp += __shfl_xor(erp, 1); erp += __shfl_xor(erp, 2); erp += __shfl_xor(erp, 4);
      if (gn < N) {
        ushort4 ob;
        ob.x = f2b(o.x); ob.y = f2b(o.y); ob.z = f2b(o.z); ob.w = f2b(o.w);
        *(ushort4*)&hf16[(size_t)gn*128 + g*64 + 4*fq] = ob;
        if ((lane & 7) == 0) {
          int head = g*2 + ((lane >> 3) & 1);
          el[(size_t)gn*4 + head] = elp;
          er[(size_t)gn*4 + head] = erp;
        }
      }
    }
  }
}

// ---------------- bucket histogram (bucket = dst>>8), LDS-reduced ----------------
__global__ __launch_bounds__(256) void k_bhist(const int* __restrict__ dst,
                                               int* __restrict__ bcnt, int E) {
  __shared__ int lh[256];
  const int t = threadIdx.x;
  lh[t] = 0;
  __syncthreads();
  const int stride = gridDim.x * 256 * 4;
  for (int base = blockIdx.x * 256 * 4; base < E; base += stride) {
    int e = base + t * 4;
    if (e + 3 < E) {
      vi4 d = ntload_i4(&dst[e]);
      atomicAdd(&lh[d.x >> 8], 1); atomicAdd(&lh[d.y >> 8], 1);
      atomicAdd(&lh[d.z >> 8], 1); atomicAdd(&lh[d.w >> 8], 1);
    } else if (e < E) {
      for (int k = e; k < E; ++k) atomicAdd(&lh[dst[k] >> 8], 1);
    }
  }
  __syncthreads();
  if (lh[t]) atomicAdd(&bcnt[t], lh[t]);
}

// ---------------- bucket scan: boff (excl), bcur seed, offsets[N]=E sentinel ----
__global__ __launch_bounds__(256) void k_bscan(const int* __restrict__ bcnt,
    int* __restrict__ boff, int* __restrict__ bcur, int* __restrict__ offsets,
    int E, int N) {
  __shared__ int tmp[256];
  const int t = threadIdx.x;
  int v = bcnt[t];
  tmp[t] = v;
  __syncthreads();
  for (int off = 1; off < 256; off <<= 1) {
    int x = (t >= off) ? tmp[t - off] : 0;
    __syncthreads();
    tmp[t] += x;
    __syncthreads();
  }
  int ex = tmp[t] - v;
  boff[t] = ex;
  bcur[t] = ex;
  if (t == 255) boff[256] = E;
  if (t == 0)   offsets[N] = E;
}

// ---------------- pass 1: bin edges by bucket (LDS sort, coalesced staging writes) ----
// staging word: (dst&255)<<24 | src   (src < 2^24)
#define TILE 4096
__global__ __launch_bounds__(1024) void k_bin(
    const int* __restrict__ src, const int* __restrict__ dst,
    int* __restrict__ bcur, unsigned int* __restrict__ staging, int E)
{
  __shared__ unsigned int lpack[TILE];
  __shared__ unsigned char lbkt[TILE];
  __shared__ unsigned short sidx[TILE];
  __shared__ int lhist[256], lbase[256], lcur[256], gbase[256];

  const int t = threadIdx.x;
  const int e0 = blockIdx.x * TILE;
  const int cnt = min(TILE, E - e0);

  if (t < 256) lhist[t] = 0;
  __syncthreads();

  for (int i = t; i < cnt; i += 1024) {
    int s = __builtin_nontemporal_load(&src[e0 + i]);
    int d = __builtin_nontemporal_load(&dst[e0 + i]);
    lpack[i] = ((unsigned)(d & 255) << 24) | (unsigned)s;
    int b = d >> 8;
    lbkt[i] = (unsigned char)b;
    atomicAdd(&lhist[b], 1);
  }
  __syncthreads();

  __shared__ int ltmp[256];
  if (t < 256) ltmp[t] = lhist[t];
  __syncthreads();
  for (int off = 1; off < 256; off <<= 1) {
    int x = 0;
    if (t < 256 && t >= off) x = ltmp[t - off];
    __syncthreads();
    if (t < 256) ltmp[t] += x;
    __syncthreads();
  }
  if (t < 256) { lbase[t] = ltmp[t] - lhist[t]; lcur[t] = ltmp[t] - lhist[t]; }
  __syncthreads();

  for (int i = t; i < cnt; i += 1024) {
    int p = atomicAdd(&lcur[lbkt[i]], 1);
    sidx[p] = (unsigned short)i;
  }
  if (t < 256) {
    int c = lhist[t];
    gbase[t] = c ? atomicAdd(&bcur[t], c) : 0;
  }
  __syncthreads();

  for (int p = t; p < cnt; p += 1024) {
    int j = sidx[p];
    int b = lbkt[j];
    staging[gbase[b] + (p - lbase[b])] = lpack[j];
  }
}

// ---------------- pass 2: per-bucket counting sort -> esrc + per-node offsets ----
#define BKT_CAP 8192
__global__ __launch_bounds__(1024) void k_debin(
    const unsigned int* __restrict__ staging, const int* __restrict__ boff,
    int* __restrict__ esrc, int* __restrict__ offsets, int N, int E)
{
  __shared__ int lout[BKT_CAP];
  __shared__ int lhist[256], lexcl[256], lcur[256];

  const int t = threadIdx.x;
  const int b = blockIdx.x;
  const int n0 = b << 8;
  const int nb = min(256, N - n0);
  const int out_start = boff[b];
  const int cnt = boff[b + 1] - out_start;

  if (t < 256) lhist[t] = 0;
  __syncthreads();

  // local per-node histogram from staging
  for (int i = t; i < cnt; i += 1024)
    atomicAdd(&lhist[staging[out_start + i] >> 24], 1);
  __syncthreads();

  // scan 256
  if (t < 256) lexcl[t] = lhist[t];
  __syncthreads();
  for (int off = 1; off < 256; off <<= 1) {
    int x = 0;
    if (t < 256 && t >= off) x = lexcl[t - off];
    __syncthreads();
    if (t < 256) lexcl[t] += x;
    __syncthreads();
  }
  if (t < 256) {
    int ex = lexcl[t] - lhist[t];
    lexcl[t] = ex;
    lcur[t]  = ex;
  }
  __syncthreads();

  if (cnt <= BKT_CAP) {
    for (int i = t; i < cnt; i += 1024) {
      unsigned int w = staging[out_start + i];
      int p = atomicAdd(&lcur[w >> 24], 1);
      lout[p] = (int)(w & 0x00FFFFFFu);
    }
    __syncthreads();
    for (int i = t; i < cnt; i += 1024)
      esrc[out_start + i] = lout[i];
  } else {
    for (int i = t; i < cnt; i += 1024) {
      unsigned int w = staging[out_start + i];
      int p = atomicAdd(&lcur[w >> 24], 1);
      esrc[out_start + p] = (int)(w & 0x00FFFFFFu);
    }
  }
  if (t < nb) offsets[n0 + t] = out_start + lexcl[t];
}

// ---------------- K2: per-dst softmax + aggregation (1 wave per node) ----------------
__global__ __launch_bounds__(256) void k_aggr(
    const int* __restrict__ esrc, const int* __restrict__ offsets,
    const unsigned short* __restrict__ hf16, const float* __restrict__ el, const float* __restrict__ er,
    float* __restrict__ out, float* __restrict__ mr, int N)
{
  __shared__ float as[4][64][4];
  __shared__ int   es[4][64];
  const int wave = threadIdx.x >> 6, lane = threadIdx.x & 63;
  const int v = blockIdx.x*4 + wave;
  if (v >= N) return;
  const int start = offsets[v];
  const int deg   = offsets[v + 1] - start;
  const float4 er4 = *(const float4*)&er[(size_t)v*4];

  const bool act = lane < deg;
  float4 e4 = make_float4(-1e30f, -1e30f, -1e30f, -1e30f);
  int mys = 0;
  if (act) {
    mys = esrc[start + lane];
    float4 el4 = *(const float4*)&el[(size_t)mys*4];
    e4.x = leaky(el4.x + er4.x);
    e4.y = leaky(el4.y + er4.y);
    e4.z = leaky(el4.z + er4.z);
    e4.w = leaky(el4.w + er4.w);
  }
  float4 m4 = e4;
  for (int j = lane + 64; j < deg; j += 64) {
    int s = esrc[start + j];
    float4 el4 = *(const float4*)&el[(size_t)s*4];
    m4.x = fmaxf(m4.x, leaky(el4.x + er4.x));
    m4.y = fmaxf(m4.y, leaky(el4.y + er4.y));
    m4.z = fmaxf(m4.z, leaky(el4.z + er4.z));
    m4.w = fmaxf(m4.w, leaky(el4.w + er4.w));
  }
  #pragma unroll
  for (int mm = 32; mm; mm >>= 1) {
    m4.x = fmaxf(m4.x, __shfl_xor(m4.x, mm));
    m4.y = fmaxf(m4.y, __shfl_xor(m4.y, mm));
    m4.z = fmaxf(m4.z, __shfl_xor(m4.z, mm));
    m4.w = fmaxf(m4.w, __shfl_xor(m4.w, mm));
  }
  float4 x4 = make_float4(0.f, 0.f, 0.f, 0.f);
  if (act) {
    x4.x = __expf(e4.x - m4.x);
    x4.y = __expf(e4.y - m4.y);
    x4.z = __expf(e4.z - m4.z);
    x4.w = __expf(e4.w - m4.w);
  }
  float4 s4 = x4;
  for (int j = lane + 64; j < deg; j += 64) {
    int s = esrc[start + j];
    float4 el4 = *(const float4*)&el[(size_t)s*4];
    s4.x += __expf(leaky(el4.x + er4.x) - m4.x);
    s4.y += __expf(leaky(el4.y + er4.y) - m4.y);
    s4.z += __expf(leaky(el4.z + er4.z) - m4.z);
    s4.w += __expf(leaky(el4.w + er4.w) - m4.w);
  }
  #pragma unroll
  for (int mm = 32; mm; mm >>= 1) {
    s4.x += __shfl_xor(s4.x, mm);
    s4.y += __shfl_xor(s4.y, mm);
    s4.z += __shfl_xor(s4.z, mm);
    s4.w += __shfl_xor(s4.w, mm);
  }
  const float4 r4 = make_float4(1.f/s4.x, 1.f/s4.y, 1.f/s4.z, 1.f/s4.w);

  if (act) {
    float4 a4 = make_float4(x4.x*r4.x, x4.y*r4.y, x4.z*r4.z, x4.w*r4.w);
    *(float4*)&as[wave][lane][0] = a4;
    es[wave][lane] = mys;
  }
  if (lane == 0) *(float4*)&mr[(size_t)v*8]     = m4;
  if (lane == 1) *(float4*)&mr[(size_t)v*8 + 4] = r4;

  const int g = lane >> 3;
  const int l = lane & 7;
  const int head = l >> 1;
  float acc[16];
  #pragma unroll
  for (int k = 0; k < 16; ++k) acc[k] = 0.f;

  const int degL = deg < 64 ? deg : 64;
  {
    int je = g;
    int jec = je < degL ? je : 0;
    int sj = es[wave][jec];
    float a = je < degL ? as[wave][jec][head] : 0.f;
    const unsigned short* hp = &hf16[(size_t)sj*128 + 16*l];
    uint4 q0 = *(const uint4*)hp;
    uint4 q1 = *(const uint4*)(hp + 8);
    for (int j = 0; j < degL; j += 8) {
      int je2 = j + 8 + g;
      int jec2 = je2 < degL ? je2 : 0;
      int s2 = es[wave][jec2];
      float a2 = je2 < degL ? as[wave][jec2][head] : 0.f;
      const unsigned short* hp2 = &hf16[(size_t)s2*128 + 16*l];
      uint4 p0 = *(const uint4*)hp2;
      uint4 p1 = *(const uint4*)(hp2 + 8);
      acc[0]  += a*b2f_lo(q0.x); acc[1]  += a*b2f_hi(q0.x);
      acc[2]  += a*b2f_lo(q0.y); acc[3]  += a*b2f_hi(q0.y);
      acc[4]  += a*b2f_lo(q0.z); acc[5]  += a*b2f_hi(q0.z);
      acc[6]  += a*b2f_lo(q0.w); acc[7]  += a*b2f_hi(q0.w);
      acc[8]  += a*b2f_lo(q1.x); acc[9]  += a*b2f_hi(q1.x);
      acc[10] += a*b2f_lo(q1.y); acc[11] += a*b2f_hi(q1.y);
      acc[12] += a*b2f_lo(q1.z); acc[13] += a*b2f_hi(q1.z);
      acc[14] += a*b2f_lo(q1.w); acc[15] += a*b2f_hi(q1.w);
      q0 = p0; q1 = p1; a = a2;
    }
  }
  for (int j = 64; j < deg; j += 8) {
    const int je = j + g;
    const bool valid = je < deg;
    int s = esrc[start + (valid ? je : 0)];
    float mh  = sel4(m4, head), rh = sel4(r4, head), erh = sel4(er4, head);
    float a = __expf(leaky(el[(size_t)s*4 + head] + erh) - mh) * rh;
    if (!valid) a = 0.f;
    const unsigned short* hp = &hf16[(size_t)s*128 + 16*l];
    uint4 q0 = *(const uint4*)hp;
    uint4 q1 = *(const uint4*)(hp + 8);
    acc[0]  += a*b2f_lo(q0.x); acc[1]  += a*b2f_hi(q0.x);
    acc[2]  += a*b2f_lo(q0.y); acc[3]  += a*b2f_hi(q0.y);
    acc[4]  += a*b2f_lo(q0.z); acc[5]  += a*b2f_hi(q0.z);
    acc[6]  += a*b2f_lo(q0.w); acc[7]  += a*b2f_hi(q0.w);
    acc[8]  += a*b2f_lo(q1.x); acc[9]  += a*b2f_hi(q1.x);
    acc[10] += a*b2f_lo(q1.y); acc[11] += a*b2f_hi(q1.y);
    acc[12] += a*b2f_lo(q1.z); acc[13] += a*b2f_hi(q1.z);
    acc[14] += a*b2f_lo(q1.w); acc[15] += a*b2f_hi(q1.w);
  }

  #pragma unroll
  for (int k = 0; k < 16; ++k) {
    acc[k] += __shfl_xor(acc[k], 8);
    acc[k] += __shfl_xor(acc[k], 16);
    acc[k] += __shfl_xor(acc[k], 32);
  }
  if (g == 0) {
    float* op = &out[(size_t)v*128 + 16*l];
    ntstore_f4(op,      acc[0],  acc[1],  acc[2],  acc[3]);
    ntstore_f4(op + 4,  acc[4],  acc[5],  acc[6],  acc[7]);
    ntstore_f4(op + 8,  acc[8],  acc[9],  acc[10], acc[11]);
    ntstore_f4(op + 12, acc[12], acc[13], acc[14], acc[15]);
  }
}

// ---------------- K3: coalesced attention output (original edge order) ----------------
__global__ void k_attn(const int* __restrict__ src, const int* __restrict__ dst,
                       const float* __restrict__ el, const float* __restrict__ er,
                       const float* __restrict__ mr, float* __restrict__ a_out, int E) {
  int e = blockIdx.x*256 + threadIdx.x;
  if (e >= E) return;
  int s = __builtin_nontemporal_load(&src[e]);
  int d = __builtin_nontemporal_load(&dst[e]);
  float4 el4 = *(const float4*)&el[(size_t)s*4];
  float4 er4 = *(const float4*)&er[(size_t)d*4];
  float4 m4  = *(const float4*)&mr[(size_t)d*8];
  float4 r4  = *(const float4*)&mr[(size_t)d*8 + 4];
  float ax = __expf(leaky(el4.x + er4.x) - m4.x) * r4.x;
  float ay = __expf(leaky(el4.y + er4.y) - m4.y) * r4.y;
  float az = __expf(leaky(el4.z + er4.z) - m4.z) * r4.z;
  float aw = __expf(leaky(el4.w + er4.w) - m4.w) * r4.w;
  ntstore_f4(&a_out[(size_t)e*4], ax, ay, az, aw);
}

extern "C" void kernel_launch(void* const* d_in, const int* in_sizes, int n_in,
                              void* d_out, int out_size, void* d_ws, size_t ws_size,
                              hipStream_t stream) {
  const float* h      = (const float*)d_in[0];
  const float* fcw    = (const float*)d_in[1];
  const float* attn_l = (const float*)d_in[2];
  const float* attn_r = (const float*)d_in[3];
  const int*   src    = (const int*)d_in[4];
  const int*   dst    = (const int*)d_in[5];
  const int N = in_sizes[0] / 128;
  const int E = in_sizes[4];
  const int B = (N + 255) >> 8;    // buckets (assumes N <= 65536)

  float* out   = (float*)d_out;
  float* a_out = out + (size_t)N*128;

  char* w = (char*)d_ws;
  unsigned short* hf16 = (unsigned short*)w; w += (size_t)N*128*sizeof(unsigned short);
  float* el      = (float*)w; w += (size_t)N*4*sizeof(float);
  float* er      = (float*)w; w += (size_t)N*4*sizeof(float);
  float* mr      = (float*)w; w += (size_t)N*8*sizeof(float);
  int*   esrc    = (int*)w;   w += (size_t)E*sizeof(int);
  unsigned int* staging = (unsigned int*)w; w += (size_t)E*sizeof(unsigned int);
  int*   offsets = (int*)w;   w += (size_t)(N + 1)*sizeof(int);
  int*   boff    = (int*)w;   w += 257*sizeof(int);
  int*   bcur    = (int*)w;   w += 256*sizeof(int);
  int*   bcnt    = (int*)w;   w += 256*sizeof(int);

  hipMemsetAsync(bcnt, 0, 256*sizeof(int), stream);

  k_proj<<<(N + 63)/64, 256, 0, stream>>>(h, fcw, attn_l, attn_r, hf16, el, er, N);

  k_bhist<<<256, 256, 0, stream>>>(dst, bcnt, E);
  k_bscan<<<1, 256, 0, stream>>>(bcnt, boff, bcur, offsets, E, N);
  k_bin<<<(E + TILE - 1)/TILE, 1024, 0, stream>>>(src, dst, bcur, staging, E);
  k_debin<<<B, 1024, 0, stream>>>(staging, boff, esrc, offsets, N, E);

  k_aggr<<<(N + 3)/4, 256, 0, stream>>>(esrc, offsets, hf16, el, er, out, mr, N);

  k_attn<<<(E + 255)/256, 256, 0, stream>>>(src, dst, el, er, mr, a_out, E);
}